// Round 1
// baseline (120.642 us; speedup 1.0000x reference)
//
#include <hip/hip_runtime.h>
#include <hip/hip_bf16.h>

typedef __bf16 bf16x8 __attribute__((ext_vector_type(8)));
typedef __bf16 bf16x4 __attribute__((ext_vector_type(4)));
typedef float f32x4 __attribute__((ext_vector_type(4)));

#define WORLD 8
#define M_DIM 8192
#define N_DIM 2048
#define KL 256
#define K_TOT 2048   // WORLD * KL

#define BM 128
#define BN 128
#define BK 64

#define AS1 __attribute__((address_space(1)))
#define AS3 __attribute__((address_space(3)))

// ---------------------------------------------------------------------------
// Pass 1: fp32 -> bf16 conversion + rank-dim gather.
//   Abf[m][r*256+k] = bf16(A[r][m][k])   -> [8192][2048] bf16 (32 MiB)
//   Wbf[n][r*256+k] = bf16(W[r][n][k])   -> [2048][2048] bf16 ( 8 MiB)
// Each thread handles one float4 (16B read, 8B write), fully coalesced.
// ---------------------------------------------------------------------------
__global__ __launch_bounds__(256) void GemmRS_convert_kernel(
    const float* __restrict__ A,
    const float* __restrict__ W,
    __bf16* __restrict__ Abf,
    __bf16* __restrict__ Wbf)
{
    const long long GA = (long long)WORLD * M_DIM * KL / 4;  // 4194304 groups
    const long long GW = (long long)WORLD * N_DIM * KL / 4;  // 1048576 groups
    const long long stride = (long long)gridDim.x * blockDim.x;
    for (long long g = (long long)blockIdx.x * blockDim.x + threadIdx.x;
         g < GA + GW; g += stride) {
        if (g < GA) {
            const long long e = g * 4;                 // flat elem idx in A
            const int k = (int)(e & (KL - 1));         // e % 256
            const int m = (int)((e >> 8) & (M_DIM - 1));
            const int r = (int)(e >> 21);              // / (8192*256)
            const float4 v = *reinterpret_cast<const float4*>(A + e);
            bf16x4 o;
            o[0] = (__bf16)v.x; o[1] = (__bf16)v.y;
            o[2] = (__bf16)v.z; o[3] = (__bf16)v.w;
            *reinterpret_cast<bf16x4*>(Abf + (size_t)m * K_TOT + r * KL + k) = o;
        } else {
            const long long e = (g - GA) * 4;          // flat elem idx in W
            const int k = (int)(e & (KL - 1));
            const int n = (int)((e >> 8) & (N_DIM - 1));
            const int r = (int)(e >> 19);              // / (2048*256)
            const float4 v = *reinterpret_cast<const float4*>(W + e);
            bf16x4 o;
            o[0] = (__bf16)v.x; o[1] = (__bf16)v.y;
            o[2] = (__bf16)v.z; o[3] = (__bf16)v.w;
            *reinterpret_cast<bf16x4*>(Wbf + (size_t)n * K_TOT + r * KL + k) = o;
        }
    }
}

// ---------------------------------------------------------------------------
// Pass 2: C[m][n] = sum_k Abf[m][k] * Wbf[n][k]   (fp32 accumulate/output)
// m97 structure: 128x128 tile, BK=64, 4 waves (2x2), each wave 64x64 out,
// v_mfma_f32_16x16x32_bf16, global_load_lds width=16, linear LDS,
// 2 barriers per K-step.
// ---------------------------------------------------------------------------
__global__ __launch_bounds__(256) void GemmRS_gemm_kernel(
    const __bf16* __restrict__ Abf,   // [M][K_TOT]
    const __bf16* __restrict__ Wbf,   // [N][K_TOT]
    float* __restrict__ C)            // [M][N]
{
    __shared__ __bf16 As[BM * BK];    // 16 KiB, row-major [128][64]
    __shared__ __bf16 Bs[BN * BK];    // 16 KiB

    const int tid  = threadIdx.x;
    const int lane = tid & 63;
    const int wave = tid >> 6;        // 0..3
    const int wm   = wave >> 1;       // wave row (0..1)
    const int wn   = wave & 1;        // wave col (0..1)

    const int tile_n = blockIdx.x & (N_DIM / BN - 1);  // 0..15
    const int tile_m = blockIdx.x >> 4;                // 0..63
    const int m0 = tile_m * BM;
    const int n0 = tile_n * BN;

    // staging geometry: each global_load_lds moves 1 KiB (64 lanes x 16 B)
    // = 8 rows x 128 B of a [*][64]-bf16 row-major tile.
    const int ld_row = lane >> 3;          // 0..7 within a chunk
    const int ld_col = (lane & 7) * 8;     // element col within BK

    const __bf16* aSrc = Abf + ((size_t)(m0 + ld_row)) * K_TOT + ld_col;
    const __bf16* bSrc = Wbf + ((size_t)(n0 + ld_row)) * K_TOT + ld_col;

    f32x4 acc[4][4];
    const f32x4 zero = {0.0f, 0.0f, 0.0f, 0.0f};
#pragma unroll
    for (int i = 0; i < 4; ++i)
#pragma unroll
        for (int j = 0; j < 4; ++j)
            acc[i][j] = zero;

    // MFMA fragment geometry (16x16x32): lane holds row (lane&15),
    // k = (lane>>4)*8 .. +8 (one ds_read_b128).
    const int fr = lane & 15;
    const int fk = (lane >> 4) * 8;

    for (int k0 = 0; k0 < K_TOT; k0 += BK) {
        __syncthreads();   // previous compute done before overwriting LDS
#pragma unroll
        for (int s = 0; s < 4; ++s) {
            const int c = s * 4 + wave;    // chunk 0..15
            __builtin_amdgcn_global_load_lds(
                (const AS1 void*)(aSrc + (size_t)(c * 8) * K_TOT + k0),
                (AS3 void*)((char*)As + c * 1024),
                16, 0, 0);
        }
#pragma unroll
        for (int s = 0; s < 4; ++s) {
            const int c = s * 4 + wave;
            __builtin_amdgcn_global_load_lds(
                (const AS1 void*)(bSrc + (size_t)(c * 8) * K_TOT + k0),
                (AS3 void*)((char*)Bs + c * 1024),
                16, 0, 0);
        }
        __syncthreads();   // staging visible (compiler drains vmcnt)

#pragma unroll
        for (int kk = 0; kk < BK; kk += 32) {
            bf16x8 af[4], bfr[4];
#pragma unroll
            for (int i = 0; i < 4; ++i)
                af[i] = *reinterpret_cast<const bf16x8*>(
                    &As[(wm * 64 + i * 16 + fr) * BK + kk + fk]);
#pragma unroll
            for (int j = 0; j < 4; ++j)
                bfr[j] = *reinterpret_cast<const bf16x8*>(
                    &Bs[(wn * 64 + j * 16 + fr) * BK + kk + fk]);
#pragma unroll
            for (int i = 0; i < 4; ++i)
#pragma unroll
                for (int j = 0; j < 4; ++j)
                    acc[i][j] = __builtin_amdgcn_mfma_f32_16x16x32_bf16(
                        af[i], bfr[j], acc[i][j], 0, 0, 0);
        }
    }

    // Epilogue: C/D layout (16x16x32): col = lane&15, row = (lane>>4)*4 + reg.
    const int crow = (lane >> 4) * 4;
    const int ccol = lane & 15;
#pragma unroll
    for (int i = 0; i < 4; ++i)
#pragma unroll
        for (int j = 0; j < 4; ++j)
#pragma unroll
            for (int q = 0; q < 4; ++q)
                C[(size_t)(m0 + wm * 64 + i * 16 + crow + q) * N_DIM
                  + (n0 + wn * 64 + j * 16 + ccol)] = acc[i][j][q];
}

extern "C" void kernel_launch(void* const* d_in, const int* in_sizes, int n_in,
                              void* d_out, int out_size, void* d_ws, size_t ws_size,
                              hipStream_t stream) {
    const float* A = (const float*)d_in[0];   // [8][8192][256] fp32
    const float* W = (const float*)d_in[1];   // [8][2048][256] fp32
    float* C = (float*)d_out;                 // [8][1024][2048] fp32 == [8192][2048]

    __bf16* Abf = (__bf16*)d_ws;                                      // 32 MiB
    __bf16* Wbf = (__bf16*)((char*)d_ws + (size_t)M_DIM * K_TOT * 2); // + 8 MiB

    GemmRS_convert_kernel<<<2048, 256, 0, stream>>>(A, W, Abf, Wbf);
    GemmRS_gemm_kernel<<<(M_DIM / BM) * (N_DIM / BN), 256, 0, stream>>>(Abf, Wbf, C);
}

// Round 2
// 83.279 us; speedup vs baseline: 1.4486x; 1.4486x over previous
//
#include <hip/hip_runtime.h>
#include <hip/hip_bf16.h>

typedef __bf16 bf16x8 __attribute__((ext_vector_type(8)));
typedef __bf16 bf16x4 __attribute__((ext_vector_type(4)));
typedef float f32x4 __attribute__((ext_vector_type(4)));

#define WORLD 8
#define M_DIM 8192
#define N_DIM 2048
#define KL 256
#define K_TOT 2048

#define BM 256
#define BN 256
#define BK 64
#define NT (K_TOT / BK)   // 32 K-tiles
#define NITER (NT / 2)    // 16 iterations, 2 tiles each

#define AS1 __attribute__((address_space(1)))
#define AS3 __attribute__((address_space(3)))

#define BAR()    __builtin_amdgcn_s_barrier()
#define LGKM0()  do { asm volatile("s_waitcnt lgkmcnt(0)" ::: "memory"); \
                      __builtin_amdgcn_sched_barrier(0); } while (0)
#define VMCNT4() asm volatile("s_waitcnt vmcnt(4)" ::: "memory")
#define PRIO1()  __builtin_amdgcn_s_setprio(1)
#define PRIO0()  __builtin_amdgcn_s_setprio(0)

// ---------------------------------------------------------------------------
// Pass 1: fp32 -> bf16 conversion + rank-dim gather (unchanged from R0).
// ---------------------------------------------------------------------------
__global__ __launch_bounds__(256) void GemmRS_convert_kernel(
    const float* __restrict__ A,
    const float* __restrict__ W,
    __bf16* __restrict__ Abf,
    __bf16* __restrict__ Wbf)
{
    const long long GA = (long long)WORLD * M_DIM * KL / 4;
    const long long GW = (long long)WORLD * N_DIM * KL / 4;
    const long long stride = (long long)gridDim.x * blockDim.x;
    for (long long g = (long long)blockIdx.x * blockDim.x + threadIdx.x;
         g < GA + GW; g += stride) {
        if (g < GA) {
            const long long e = g * 4;
            const int k = (int)(e & (KL - 1));
            const int m = (int)((e >> 8) & (M_DIM - 1));
            const int r = (int)(e >> 21);
            const float4 v = *reinterpret_cast<const float4*>(A + e);
            bf16x4 o;
            o[0] = (__bf16)v.x; o[1] = (__bf16)v.y;
            o[2] = (__bf16)v.z; o[3] = (__bf16)v.w;
            *reinterpret_cast<bf16x4*>(Abf + (size_t)m * K_TOT + r * KL + k) = o;
        } else {
            const long long e = (g - GA) * 4;
            const int k = (int)(e & (KL - 1));
            const int n = (int)((e >> 8) & (N_DIM - 1));
            const int r = (int)(e >> 19);
            const float4 v = *reinterpret_cast<const float4*>(W + e);
            bf16x4 o;
            o[0] = (__bf16)v.x; o[1] = (__bf16)v.y;
            o[2] = (__bf16)v.z; o[3] = (__bf16)v.w;
            *reinterpret_cast<bf16x4*>(Wbf + (size_t)n * K_TOT + r * KL + k) = o;
        }
    }
}

// ---------------------------------------------------------------------------
// Pass 2: 256x256 8-phase bf16 GEMM (T1+T2+T3+T4+T5).
// ---------------------------------------------------------------------------

// inline-asm LDS read (keeps compiler from inserting vmcnt drains for aliasing)
__device__ __forceinline__ bf16x8 ldsread(const __bf16* p) {
    bf16x8 r;
    unsigned a = (unsigned)(unsigned long long)
        (const AS3 __bf16*)p;
    asm volatile("ds_read_b128 %0, %1" : "=v"(r) : "v"(a));
    return r;
}

// Stage one 128x64 half-tile (16 KiB) via 2 global_load_lds per wave.
// LDS dest is LINEAR; the swizzle (granule ^= row&7) is applied on the
// per-lane GLOBAL source column (m173 pattern).
__device__ __forceinline__ void stage_half(const __bf16* srcbase, __bf16* dstbase,
                                           int lane, int wave) {
    const int rl = lane >> 3;                 // 0..7 (row within 8-row slab)
    const int g  = (lane & 7) ^ rl;           // swizzled 16B-granule
    const __bf16* s = srcbase + (size_t)(wave * 8 + rl) * K_TOT + g * 8;
#pragma unroll
    for (int j = 0; j < 2; ++j) {
        __builtin_amdgcn_global_load_lds(
            (const AS1 void*)(s + (size_t)(j * 64) * K_TOT),
            (AS3 void*)(dstbase + (j * 64 + wave * 8) * BK),
            16, 0, 0);
    }
}

template<int MH>
__device__ __forceinline__ void read_A(bf16x8 (&a)[4][2], const __bf16* Lbase,
                                       int arow, int gk0, int gk1) {
#pragma unroll
    for (int f = 0; f < 4; ++f) {
        const __bf16* rp = Lbase + arow + (MH * 4 + f) * 16 * BK;
        a[f][0] = ldsread(rp + gk0);
        a[f][1] = ldsread(rp + gk1);
    }
}

__device__ __forceinline__ void read_B(bf16x8 (&b)[4][2], const __bf16* Lbase,
                                       int brow, int gk0, int gk1) {
#pragma unroll
    for (int f = 0; f < 4; ++f) {
        const __bf16* rp = Lbase + brow + f * 16 * BK;
        b[f][0] = ldsread(rp + gk0);
        b[f][1] = ldsread(rp + gk1);
    }
}

template<int MH, int NH>
__device__ __forceinline__ void mma_quad(f32x4 (&acc)[8][4],
                                         bf16x8 (&a)[4][2], bf16x8 (&b)[4][2]) {
#pragma unroll
    for (int f = 0; f < 4; ++f)
#pragma unroll
        for (int j = 0; j < 2; ++j) {
            f32x4 c = acc[MH * 4 + f][NH * 2 + j];
            c = __builtin_amdgcn_mfma_f32_16x16x32_bf16(a[f][0], b[NH * 2 + j][0], c, 0, 0, 0);
            c = __builtin_amdgcn_mfma_f32_16x16x32_bf16(a[f][1], b[NH * 2 + j][1], c, 0, 0, 0);
            acc[MH * 4 + f][NH * 2 + j] = c;
        }
}

__global__ __launch_bounds__(512, 2) void GemmRS_gemm_kernel(
    const __bf16* __restrict__ Abf,   // [M][K_TOT]
    const __bf16* __restrict__ Wbf,   // [N][K_TOT]
    float* __restrict__ C)            // [M][N]
{
    __shared__ __bf16 lds[2][2][BM * BK];   // [buf][A=0/B=1][256*64] = 128 KiB

    const int tid  = threadIdx.x;
    const int lane = tid & 63;
    const int wave = tid >> 6;      // 0..7
    const int wr   = wave >> 2;     // 0..1  (m half: 128 rows)
    const int wc   = wave & 3;      // 0..3  (n quarter: 64 cols)

    // T1: XCD-aware bijective swizzle (256 blocks, 256%8==0)
    const int bid = blockIdx.x;
    const int swz = (bid & 7) * 32 + (bid >> 3);
    const int tm = swz >> 3;        // 0..31
    const int tn = swz & 7;         // 0..7
    const size_t m0 = (size_t)tm * BM;
    const size_t n0 = (size_t)tn * BN;

    const __bf16* aptr = Abf + m0 * K_TOT;
    const __bf16* bptr = Wbf + n0 * K_TOT;

    __bf16* LA0 = &lds[0][0][0];
    __bf16* LB0 = &lds[0][1][0];
    __bf16* LA1 = &lds[1][0][0];
    __bf16* LB1 = &lds[1][1][0];

    auto ST = [&](__bf16* dst, const __bf16* srcp, int h, int t) {
        stage_half(srcp + (size_t)(h * 128) * K_TOT + t * BK,
                   dst + h * 128 * BK, lane, wave);
    };

    // per-thread LDS read offsets (elements)
    const int r15 = lane & 15;
    const int g2  = lane >> 4;      // 0..3
    const int l7  = lane & 7;
    const int gk0 = ((g2)     ^ l7) * 8;    // ks=0 granule, swizzled
    const int gk1 = ((4 + g2) ^ l7) * 8;    // ks=1
    const int arow = (wr * 128 + r15) * BK;
    const int brow = (wc * 64  + r15) * BK;

    f32x4 acc[8][4];
#pragma unroll
    for (int i = 0; i < 8; ++i)
#pragma unroll
        for (int j = 0; j < 4; ++j)
            acc[i][j] = (f32x4){0.f, 0.f, 0.f, 0.f};

    bf16x8 a[4][2], b[4][2];

    // ---- prologue: buf0 <- tile0 (A+B), buf1.B <- tile1 ----
    ST(LA0, aptr, 0, 0);
    ST(LA0, aptr, 1, 0);
    ST(LB0, bptr, 0, 0);
    ST(LB0, bptr, 1, 0);
    ST(LB1, bptr, 0, 1);
    ST(LB1, bptr, 1, 1);
    VMCNT4();               // tile0's 8 loads landed; buf1.B (4) still flying
    BAR();

    for (int i = 0; i < NITER; ++i) {
        const int t1 = 2 * i + 1;                            // always < NT
        const int t2 = (2 * i + 2 < NT) ? 2 * i + 2 : NT - 1;
        const int t3 = (2 * i + 3 < NT) ? 2 * i + 3 : NT - 1;

        // ================= tile-group 0: consume buf0 (tile 2i) ============
        // P0
        read_A<0>(a, LA0, arow, gk0, gk1);
        read_B(b, LB0, brow, gk0, gk1);
        ST(LA1, aptr, 0, t1);
        BAR(); LGKM0();
        PRIO1(); mma_quad<0, 0>(acc, a, b); PRIO0();
        BAR();
        // P1
        ST(LA1, aptr, 1, t1);
        BAR(); LGKM0();
        PRIO1(); mma_quad<0, 1>(acc, a, b); PRIO0();
        BAR();
        // P2
        read_A<1>(a, LA0, arow, gk0, gk1);
        ST(LB0, bptr, 0, t2);
        BAR(); LGKM0();
        PRIO1(); mma_quad<1, 1>(acc, a, b); PRIO0();
        BAR();
        // P3
        ST(LB0, bptr, 1, t2);
        BAR(); LGKM0();
        PRIO1(); mma_quad<1, 0>(acc, a, b); PRIO0();
        VMCNT4();           // buf1 (A:P0/P1, B:prev P6/P7) landed; 4 newest fly
        BAR();

        // ================= tile-group 1: consume buf1 (tile 2i+1) ==========
        // P4
        read_A<0>(a, LA1, arow, gk0, gk1);
        read_B(b, LB1, brow, gk0, gk1);
        ST(LA0, aptr, 0, t2);
        BAR(); LGKM0();
        PRIO1(); mma_quad<0, 0>(acc, a, b); PRIO0();
        BAR();
        // P5
        ST(LA0, aptr, 1, t2);
        BAR(); LGKM0();
        PRIO1(); mma_quad<0, 1>(acc, a, b); PRIO0();
        BAR();
        // P6
        read_A<1>(a, LA1, arow, gk0, gk1);
        ST(LB1, bptr, 0, t3);
        BAR(); LGKM0();
        PRIO1(); mma_quad<1, 1>(acc, a, b); PRIO0();
        BAR();
        // P7
        ST(LB1, bptr, 1, t3);
        BAR(); LGKM0();
        PRIO1(); mma_quad<1, 0>(acc, a, b); PRIO0();
        VMCNT4();           // buf0 (B:P2/P3, A:P4/P5) landed; buf1.B flies
        BAR();
    }

    // ---- epilogue: C/D layout col=lane&15, row=(lane>>4)*4+q ----
#pragma unroll
    for (int fa = 0; fa < 8; ++fa)
#pragma unroll
        for (int fb = 0; fb < 4; ++fb) {
            float* cp = C + (m0 + wr * 128 + fa * 16 + g2 * 4) * (size_t)N_DIM
                          + n0 + wc * 64 + fb * 16 + r15;
#pragma unroll
            for (int q = 0; q < 4; ++q)
                cp[(size_t)q * N_DIM] = acc[fa][fb][q];
        }
}

extern "C" void kernel_launch(void* const* d_in, const int* in_sizes, int n_in,
                              void* d_out, int out_size, void* d_ws, size_t ws_size,
                              hipStream_t stream) {
    (void)in_sizes; (void)n_in; (void)out_size; (void)ws_size;
    const float* A = (const float*)d_in[0];   // [8][8192][256] fp32
    const float* W = (const float*)d_in[1];   // [8][2048][256] fp32
    float* C = (float*)d_out;                 // [8192][2048] fp32

    __bf16* Abf = (__bf16*)d_ws;                                      // 32 MiB
    __bf16* Wbf = (__bf16*)((char*)d_ws + (size_t)M_DIM * K_TOT * 2); // + 8 MiB

    GemmRS_convert_kernel<<<2048, 256, 0, stream>>>(A, W, Abf, Wbf);
    GemmRS_gemm_kernel<<<(M_DIM / BM) * (N_DIM / BN), 512, 0, stream>>>(Abf, Wbf, C);
}